// Round 7
// baseline (595.564 us; speedup 1.0000x reference)
//
#include <hip/hip_runtime.h>
#include <hip/hip_fp16.h>

#define EPSBN 1e-5f
#define SH 7          // bucket = dst >> SH  (128 nodes per bucket)
#define CHUNK 16384   // edges per sort chunk
#define SCANB 256     // scan blocks

// ---------------------------------------------------------------- utilities
__global__ void k_fill(float* __restrict__ p, float v, int n) {
    int i = blockIdx.x * blockDim.x + threadIdx.x;
    if (i < n) p[i] = v;
}

// ------------------------------------------------------- bucketed count sort
// S1: per-chunk histogram over coarse buckets, bucket-major output
__launch_bounds__(1024)
__global__ void k_hist(const int* __restrict__ dst, int* __restrict__ hist,
                       int E, int C, int NB) {
    __shared__ int h[1024];
    const int tid = threadIdx.x, c = blockIdx.x;
    for (int i = tid; i < NB; i += 1024) h[i] = 0;
    __syncthreads();
    const int e0 = c * CHUNK, e1 = min(e0 + CHUNK, E);
    for (int e = e0 + tid; e < e1; e += 1024) atomicAdd(&h[dst[e] >> SH], 1);
    __syncthreads();
    for (int b = tid; b < NB; b += 1024) hist[b * C + c] = h[b];
}

// S2a: per-segment sums
__launch_bounds__(256)
__global__ void k_scanA(const int* __restrict__ hist, int* __restrict__ bsum, int M) {
    __shared__ int part[256];
    const int b = blockIdx.x, t = threadIdx.x;
    const int seg = (M + SCANB - 1) / SCANB;
    const int lo = b * seg, hi = min(lo + seg, M);
    int s = 0;
    for (int i = lo + t; i < hi; i += 256) s += hist[i];
    part[t] = s;
    __syncthreads();
    for (int d = 128; d > 0; d >>= 1) {
        if (t < d) part[t] += part[t + d];
        __syncthreads();
    }
    if (t == 0) bsum[b] = part[0];
}

// S2b: exclusive scan of bsum[SCANB], single block
__launch_bounds__(256)
__global__ void k_scanB(int* __restrict__ bsum) {
    __shared__ int sh[256];
    const int t = threadIdx.x;
    sh[t] = bsum[t];
    __syncthreads();
    for (int d = 1; d < 256; d <<= 1) {
        int v = (t >= d) ? sh[t - d] : 0;
        __syncthreads();
        sh[t] += v;
        __syncthreads();
    }
    bsum[t] = (t == 0) ? 0 : sh[t - 1];
}

// S2c: per-segment exclusive scan (in place) + bsum offset; off[N]=E
__launch_bounds__(256)
__global__ void k_scanC(int* __restrict__ hist, const int* __restrict__ bsum,
                        int* __restrict__ off, int M, int E, int N) {
    __shared__ int part[256];
    const int b = blockIdx.x, t = threadIdx.x;
    const int seg = (M + SCANB - 1) / SCANB;
    const int lo = b * seg, hi = min(lo + seg, M);
    const int per = (seg + 255) >> 8;
    const int tl = lo + t * per, th = min(tl + per, hi);
    int s = 0;
    for (int i = tl; i < th; ++i) s += hist[i];
    part[t] = s;
    __syncthreads();
    for (int d = 1; d < 256; d <<= 1) {
        int v = (t >= d) ? part[t - d] : 0;
        __syncthreads();
        part[t] += v;
        __syncthreads();
    }
    int run = bsum[b] + ((t == 0) ? 0 : part[t - 1]);
    for (int i = tl; i < th; ++i) {
        int v = hist[i];
        hist[i] = run;
        run += v;
    }
    if (b == 0 && t == 0) off[N] = E;
}

// S3: scatter packed (dstloc<<18|src) into bucket-grouped order
__launch_bounds__(1024)
__global__ void k_sort(const int* __restrict__ src, const int* __restrict__ dst,
                       const int* __restrict__ hist, int* __restrict__ spk,
                       int E, int C, int NB) {
    __shared__ int cur[1024];
    const int tid = threadIdx.x, c = blockIdx.x;
    for (int b = tid; b < NB; b += 1024) cur[b] = hist[b * C + c];
    __syncthreads();
    const int e0 = c * CHUNK, e1 = min(e0 + CHUNK, E);
    for (int e = e0 + tid; e < e1; e += 1024) {
        const int d = dst[e];
        const int pos = atomicAdd(&cur[d >> SH], 1);
        spk[pos] = ((d & 127) << 18) | src[e];
    }
}

// S4: one block per bucket -> per-node counts, off[], dis[], and final eda
__launch_bounds__(256)
__global__ void k_csr(const int* __restrict__ spk, const int* __restrict__ hist,
                      int* __restrict__ off, float* __restrict__ dis,
                      int* __restrict__ eda, int E, int C, int NB, int N) {
    __shared__ int cnt_l[128], scn[128];
    const int tid = threadIdx.x, b = blockIdx.x;
    const int node0 = b << SH;
    const int nloc = min(128, N - node0);
    const int ebeg = hist[b * C];
    const int eend = (b + 1 < NB) ? hist[(b + 1) * C] : E;
    if (tid < 128) cnt_l[tid] = 0;
    __syncthreads();
    for (int e = ebeg + tid; e < eend; e += 256) {
        atomicAdd(&cnt_l[spk[e] >> 18], 1);
    }
    __syncthreads();
    if (tid < 128) scn[tid] = cnt_l[tid];
    __syncthreads();
    for (int d = 1; d < 128; d <<= 1) {
        int v = 0;
        if (tid < 128 && tid >= d) v = scn[tid - d];
        __syncthreads();
        if (tid < 128) scn[tid] += v;
        __syncthreads();
    }
    if (tid < nloc) {
        const int excl = scn[tid] - cnt_l[tid];
        off[node0 + tid] = ebeg + excl;
        dis[node0 + tid] = rsqrtf((float)cnt_l[tid] + 1.0f);
    }
    __syncthreads();
    if (tid < 128) cnt_l[tid] = scn[tid] - cnt_l[tid];  // reuse as cursor
    __syncthreads();
    for (int e = ebeg + tid; e < eend; e += 256) {
        const int p = spk[e];
        const int r = atomicAdd(&cnt_l[p >> 18], 1);
        eda[ebeg + r] = p & 0x3FFFF;
    }
}

// ----------------------------------------------------- layer-0 special path
// x0s4[w] = dis[w] * x0[w]  (3 ch padded to float4)
__global__ void k_prex(const float* __restrict__ x0, const float* __restrict__ dis,
                       float4* __restrict__ x0s4, int N) {
    int i = blockIdx.x * blockDim.x + threadIdx.x;
    if (i >= N) return;
    const float d = dis[i];
    x0s4[i] = make_float4(d * x0[3 * i], d * x0[3 * i + 1], d * x0[3 * i + 2], 0.f);
}

// z4[w] = dis[w] * (x0s4[w] + sum_src x0s4[src])   (wave per node)
__launch_bounds__(256)
__global__ void k_gather3(const int* __restrict__ off, const int* __restrict__ eda,
                          const float* __restrict__ dis, const float4* __restrict__ x0s4,
                          float4* __restrict__ z4, int N) {
    const int lane = threadIdx.x & 63, wv = threadIdx.x >> 6;
    const int nw = gridDim.x * 4;
    for (int w = blockIdx.x * 4 + wv; w < N; w += nw) {
        const int e0 = off[w], e1 = off[w + 1];
        float a0 = 0.f, a1 = 0.f, a2 = 0.f;
        for (int e = e0 + lane; e < e1; e += 64) {
            float4 v = x0s4[eda[e]];
            a0 += v.x;
            a1 += v.y;
            a2 += v.z;
        }
        for (int d = 32; d; d >>= 1) {
            a0 += __shfl_xor(a0, d);
            a1 += __shfl_xor(a1, d);
            a2 += __shfl_xor(a2, d);
        }
        if (lane == 0) {
            const float4 sv = x0s4[w];
            const float dw = dis[w];
            z4[w] = make_float4(dw * (a0 + sv.x), dw * (a1 + sv.y), dw * (a2 + sv.z), 0.f);
        }
    }
}

// bufA = z4(N,3) @ W0(3,64), fused BN stats
__launch_bounds__(256)
__global__ void k_lin0(const float4* __restrict__ z4, const float* __restrict__ W,
                       float* __restrict__ bufA, float* __restrict__ st, int N) {
    __shared__ float Ws[3 * 64];
    __shared__ float ls[256], lq[256];
    const int tid = threadIdx.x;
    for (int i = tid; i < 192; i += 256) Ws[i] = W[i];
    __syncthreads();
    const int c = tid & 63, wv = tid >> 6;
    float s = 0.f, q = 0.f;
    for (int r = blockIdx.x * 4 + wv; r < N; r += gridDim.x * 4) {
        const float4 zr = z4[r];
        float acc = zr.x * Ws[c] + zr.y * Ws[64 + c] + zr.z * Ws[128 + c];
        bufA[(long)r * 64 + c] = acc;
        s += acc;
        q = fmaf(acc, acc, q);
    }
    ls[tid] = s;
    lq[tid] = q;
    __syncthreads();
    if (tid < 64) {
        s = ls[c] + ls[c + 64] + ls[c + 128] + ls[c + 192];
        q = lq[c] + lq[c + 64] + lq[c + 128] + lq[c + 192];
        unsafeAtomicAdd(&st[c], s);
        unsafeAtomicAdd(&st[64 + c], q);
    }
}

// --------------------------------------------------- fused (BN+ReLU) + linear
// hp = (act(X)(N,64) @ W(64,64)) * dis[row]  stored fp16.
__launch_bounds__(256)
__global__ void k_linear(const float* __restrict__ X, const float* __restrict__ W,
                         const float* __restrict__ st, const float* __restrict__ g,
                         const float* __restrict__ be, const float* __restrict__ dis,
                         __half* __restrict__ hp, int N) {
    __shared__ float Ws[64 * 64];
    __shared__ float Xs[32 * 64];
    __shared__ float scs[64], shs[64];
    const int tid = threadIdx.x;
    if (tid < 64) {
        const float inv = 1.0f / (float)N;
        const float m = st[tid] * inv;
        const float v = st[64 + tid] * inv - m * m;
        const float sc = g[tid] * rsqrtf(v + EPSBN);
        scs[tid] = sc;
        shs[tid] = fmaf(-m, sc, be[tid]);
    }
    for (int i = tid; i < 64 * 64; i += 256) Ws[i] = W[i];
    __syncthreads();
    const int r0 = blockIdx.x * 32;
    for (int i = tid; i < 32 * 64; i += 256) {
        const int r = i >> 6, c = i & 63;
        const int row = r0 + r;
        float val = (row < N) ? X[(long)row * 64 + c] : 0.f;
        Xs[i] = fmaxf(fmaf(val, scs[c], shs[c]), 0.f);
    }
    __syncthreads();
    const int c = tid & 63, wv = tid >> 6;
    for (int rr = 0; rr < 8; ++rr) {
        const int r = wv * 8 + rr;
        const int row = r0 + r;
        if (row >= N) break;
        float acc = 0.f;
#pragma unroll
        for (int k = 0; k < 64; ++k) acc = fmaf(Xs[r * 64 + k], Ws[k * 64 + c], acc);
        hp[(long)row * 64 + c] = __float2half(acc * dis[row]);
    }
}

// ------------------------------------------- CSR aggregation + fused BN stats
// half2 channels: lane = (edge-parity hi, channel-pair c2). Each load covers
// 2 edges per wave -> 2x outstanding bytes per issued instruction.
__launch_bounds__(256)
__global__ void k_gather2(const int* __restrict__ off, const int* __restrict__ eda,
                          const float* __restrict__ dis, const __half2* __restrict__ hp2,
                          float2* __restrict__ agg2, float* __restrict__ st, int N) {
    __shared__ int els[4][64];
    __shared__ float2 lsum[4][32], lsq[4][32];
    const int lane = threadIdx.x & 63;
    const int wv = threadIdx.x >> 6;
    const int c2 = lane & 31;
    const int hi = lane >> 5;
    const int nwaves = gridDim.x * 4;
    float2 sa = {0.f, 0.f}, qa = {0.f, 0.f};
    for (int w = blockIdx.x * 4 + wv; w < N; w += nwaves) {
        const int e0 = off[w], e1 = off[w + 1];
        float2 a0 = {0.f, 0.f}, a1 = {0.f, 0.f};
        {
            const float2 v = __half22float2(hp2[(long)w * 32 + c2]);
            if (!hi) a0 = v;  // self term counted once
        }
        for (int eb = e0; eb < e1; eb += 64) {
            const int mm = min(64, e1 - eb);
            if (eb + lane < e1) els[wv][lane] = eda[eb + lane];
            int j = 0;
            for (; j + 8 <= mm; j += 8) {
                const int s0 = els[wv][j + hi], s1 = els[wv][j + 2 + hi];
                const int s2 = els[wv][j + 4 + hi], s3 = els[wv][j + 6 + hi];
                const float2 v0 = __half22float2(hp2[(long)s0 * 32 + c2]);
                const float2 v1 = __half22float2(hp2[(long)s1 * 32 + c2]);
                const float2 v2 = __half22float2(hp2[(long)s2 * 32 + c2]);
                const float2 v3 = __half22float2(hp2[(long)s3 * 32 + c2]);
                a0.x += v0.x + v2.x;
                a0.y += v0.y + v2.y;
                a1.x += v1.x + v3.x;
                a1.y += v1.y + v3.y;
            }
            for (; j + 2 <= mm; j += 2) {
                const int s0 = els[wv][j + hi];
                const float2 v0 = __half22float2(hp2[(long)s0 * 32 + c2]);
                a0.x += v0.x;
                a0.y += v0.y;
            }
            if (j < mm && !hi) {  // odd leftover edge -> hi=0 half only
                const int s0 = els[wv][j];
                const float2 v0 = __half22float2(hp2[(long)s0 * 32 + c2]);
                a1.x += v0.x;
                a1.y += v0.y;
            }
        }
        float ax = a0.x + a1.x, ay = a0.y + a1.y;
        ax += __shfl_xor(ax, 32);
        ay += __shfl_xor(ay, 32);
        const float dw = dis[w];
        const float2 outv = {dw * ax, dw * ay};
        if (!hi) agg2[(long)w * 32 + c2] = outv;
        sa.x += outv.x;
        sa.y += outv.y;
        qa.x = fmaf(outv.x, outv.x, qa.x);
        qa.y = fmaf(outv.y, outv.y, qa.y);
    }
    if (!hi) {  // hi=1 lanes hold duplicate values -> ignore
        lsum[wv][c2] = sa;
        lsq[wv][c2] = qa;
    }
    __syncthreads();
    if (threadIdx.x < 32) {
        float2 S = {0.f, 0.f}, Q = {0.f, 0.f};
#pragma unroll
        for (int k = 0; k < 4; ++k) {
            S.x += lsum[k][threadIdx.x].x;
            S.y += lsum[k][threadIdx.x].y;
            Q.x += lsq[k][threadIdx.x].x;
            Q.y += lsq[k][threadIdx.x].y;
        }
        unsafeAtomicAdd(&st[2 * threadIdx.x], S.x);
        unsafeAtomicAdd(&st[2 * threadIdx.x + 1], S.y);
        unsafeAtomicAdd(&st[64 + 2 * threadIdx.x], Q.x);
        unsafeAtomicAdd(&st[64 + 2 * threadIdx.x + 1], Q.y);
    }
}

// ----------------------------------------------------- pooling (fused BN+ReLU)
__launch_bounds__(256)
__global__ void k_pool(const float* __restrict__ x, const int* __restrict__ batch,
                       const float* __restrict__ st, const float* __restrict__ g,
                       const float* __restrict__ be, float* __restrict__ poolsum,
                       float* __restrict__ counts, int N, int npw) {
    const int wid = (blockIdx.x * blockDim.x + threadIdx.x) >> 6;
    const int lane = threadIdx.x & 63;
    const int n0 = wid * npw;
    if (n0 >= N) return;
    const float inv = 1.0f / (float)N;
    const float m = st[lane] * inv;
    const float v = st[64 + lane] * inv - m * m;
    const float sc = g[lane] * rsqrtf(v + EPSBN);
    const float sh = fmaf(-m, sc, be[lane]);
    const int n1 = min(n0 + npw, N);
    float acc = 0.f, cnt = 0.f;
    int gr = batch[n0];
    for (int n = n0; n < n1; ++n) {
        int gn = batch[n];
        if (gn != gr) {
            unsafeAtomicAdd(&poolsum[(long)gr * 64 + lane], acc);
            if (lane == 0) unsafeAtomicAdd(&counts[gr], cnt);
            acc = 0.f;
            cnt = 0.f;
            gr = gn;
        }
        acc += fmaxf(fmaf(x[(long)n * 64 + lane], sc, sh), 0.f);
        cnt += 1.f;
    }
    unsafeAtomicAdd(&poolsum[(long)gr * 64 + lane], acc);
    if (lane == 0) unsafeAtomicAdd(&counts[gr], cnt);
}

// --------------------------------------------------------------------- heads
__launch_bounds__(256)
__global__ void k_heads(const float* __restrict__ poolsum, const float* __restrict__ counts,
                        const float* pW1, const float* pb1, const float* pW2, const float* pb2,
                        const float* aW1, const float* ab1, const float* aW2, const float* ab2,
                        const float* tW1, const float* tb1, const float* tW2, const float* tb2,
                        float* __restrict__ out, int G) {
    __shared__ float P[64 * 64];
    __shared__ float Hd[64 * 32];
    const int tid = threadIdx.x;
    for (int i = tid; i < G * 64; i += 256) {
        int g = i >> 6;
        P[i] = poolsum[i] / fmaxf(counts[g], 1.f);
    }
    __syncthreads();
    for (int j = 0; j < 3; ++j) {
        const float* W1 = (j == 0) ? pW1 : (j == 1) ? aW1 : tW1;
        const float* b1 = (j == 0) ? pb1 : (j == 1) ? ab1 : tb1;
        const float* W2 = (j == 0) ? pW2 : (j == 1) ? aW2 : tW2;
        const float* b2 = (j == 0) ? pb2 : (j == 1) ? ab2 : tb2;
        for (int i = tid; i < G * 32; i += 256) {
            int g = i >> 5, k = i & 31;
            float a = b1[k];
#pragma unroll
            for (int c = 0; c < 64; ++c) a = fmaf(P[g * 64 + c], W1[c * 32 + k], a);
            Hd[i] = fmaxf(a, 0.f);
        }
        __syncthreads();
        const int ow = (j == 2) ? 2 : 1;
        const int off = (j == 2) ? 2 : j;
        for (int i = tid; i < G * ow; i += 256) {
            int g = i / ow, o = i - g * ow;
            float a = b2[o];
#pragma unroll
            for (int k = 0; k < 32; ++k) a = fmaf(Hd[g * 32 + k], W2[k * ow + o], a);
            out[g * 4 + off + o] = a;
        }
        __syncthreads();
    }
}

// ====================================================================== host
extern "C" void kernel_launch(void* const* d_in, const int* in_sizes, int n_in,
                              void* d_out, int out_size, void* d_ws, size_t ws_size,
                              hipStream_t stream) {
    const int N = in_sizes[2];      // batch has N entries
    const int E = in_sizes[1] / 2;  // edge_index is [2, E]
    const int G = out_size / 4;     // output [G, 4]

    const float* x0 = (const float*)d_in[0];
    const int* ei = (const int*)d_in[1];
    const int* src = ei;
    const int* dst = ei + E;
    const int* batch = (const int*)d_in[2];

    const float* W[3] = {(const float*)d_in[3], (const float*)d_in[7], (const float*)d_in[11]};
    const float* gam[3] = {(const float*)d_in[5], (const float*)d_in[9], (const float*)d_in[13]};
    const float* bet[3] = {(const float*)d_in[6], (const float*)d_in[10], (const float*)d_in[14]};

    const float* pW1 = (const float*)d_in[15];
    const float* pb1 = (const float*)d_in[16];
    const float* pW2 = (const float*)d_in[17];
    const float* pb2 = (const float*)d_in[18];
    const float* aW1 = (const float*)d_in[19];
    const float* ab1 = (const float*)d_in[20];
    const float* aW2 = (const float*)d_in[21];
    const float* ab2 = (const float*)d_in[22];
    const float* tW1 = (const float*)d_in[23];
    const float* tb1 = (const float*)d_in[24];
    const float* tW2 = (const float*)d_in[25];
    const float* tb2 = (const float*)d_in[26];

    const int C = (E + CHUNK - 1) / CHUNK;   // sort chunks
    const int NB = (N + 127) >> SH;          // coarse buckets
    const int M = NB * C;

    // ---- workspace carve (256B aligned)
    auto align = [](size_t x) { return (x + 255) & ~(size_t)255; };
    char* w = (char*)d_ws;
    float* dis = (float*)w;      w += align((size_t)N * 4);
    float* bufA = (float*)w;     w += align((size_t)N * 64 * 4);   // fp32 agg
    __half* hp = (__half*)w;     w += align((size_t)N * 64 * 2);   // fp16 messages
    float* st = (float*)w;       w += align(3 * 128 * 4);          // st0,st1,st2
    float* poolsum = (float*)w;  w += align((size_t)G * 64 * 4);
    float* counts = (float*)w;   w += align((size_t)G * 4);
    int* off = (int*)w;          w += align((size_t)(N + 1) * 4);
    int* hist = (int*)w;         w += align((size_t)M * 4);
    int* bsum = (int*)w;         w += align((size_t)SCANB * 4);
    int* spk = (int*)w;          w += align((size_t)E * 4);        // packed sort
    int* eda = (int*)w;          w += align((size_t)E * 4);
    float4* x0s4 = (float4*)w;   w += align((size_t)N * 16);
    float4* z4 = (float4*)w;     w += align((size_t)N * 16);
    (void)ws_size;

    const int nbN = (N + 255) / 256;
    const int nb_lin = (N + 31) / 32;
    const int nb_ga = 2048;

    // ---- CSR build via bucketed counting sort (parallel scan, packed records)
    k_hist<<<C, 1024, 0, stream>>>(dst, hist, E, C, NB);
    k_scanA<<<SCANB, 256, 0, stream>>>(hist, bsum, M);
    k_scanB<<<1, 256, 0, stream>>>(bsum);
    k_scanC<<<SCANB, 256, 0, stream>>>(hist, bsum, off, M, E, N);
    k_sort<<<C, 1024, 0, stream>>>(src, dst, hist, spk, E, C, NB);
    k_csr<<<NB, 256, 0, stream>>>(spk, hist, off, dis, eda, E, C, NB, N);
    k_fill<<<2, 256, 0, stream>>>(st, 0.f, 3 * 128);

    // ---- layer 0: aggregate raw 3-channel input, then multiply W0 (+stats)
    k_prex<<<nbN, 256, 0, stream>>>(x0, dis, x0s4, N);
    k_gather3<<<512, 256, 0, stream>>>(off, eda, dis, x0s4, z4, N);
    k_lin0<<<1024, 256, 0, stream>>>(z4, W[0], bufA, st, N);

    // ---- layers 1,2 (K=64, BN of previous layer fused into staging)
    for (int l = 1; l < 3; ++l) {
        k_linear<<<nb_lin, 256, 0, stream>>>(bufA, W[l], st + (l - 1) * 128,
                                             gam[l - 1], bet[l - 1], dis, hp, N);
        k_gather2<<<nb_ga, 256, 0, stream>>>(off, eda, dis, (const __half2*)hp,
                                             (float2*)bufA, st + l * 128, N);
    }

    // ---- global mean pool (BN of layer 2 fused)
    k_fill<<<(G * 64 + 255) / 256, 256, 0, stream>>>(poolsum, 0.f, G * 64);
    k_fill<<<1, 64, 0, stream>>>(counts, 0.f, G);
    const int npw = 32;
    const int nwaves = (N + npw - 1) / npw;
    const int nb_pool = (nwaves * 64 + 255) / 256;
    k_pool<<<nb_pool, 256, 0, stream>>>(bufA, batch, st + 256, gam[2], bet[2],
                                        poolsum, counts, N, npw);

    // ---- heads
    k_heads<<<1, 256, 0, stream>>>(poolsum, counts, pW1, pb1, pW2, pb2,
                                   aW1, ab1, aW2, ab2, tW1, tb1, tW2, tb2,
                                   (float*)d_out, G);
}

// Round 8
// 505.955 us; speedup vs baseline: 1.1771x; 1.1771x over previous
//
#include <hip/hip_runtime.h>
#include <hip/hip_fp16.h>

#define EPSBN 1e-5f
#define SH 7          // bucket = dst >> SH  (128 nodes per bucket)
#define CHUNK 16384   // edges per sort chunk
#define SCANB 256     // scan blocks

// ---------------------------------------------------------------- utilities
__global__ void k_fill(float* __restrict__ p, float v, int n) {
    int i = blockIdx.x * blockDim.x + threadIdx.x;
    if (i < n) p[i] = v;
}

// ------------------------------------------------------- bucketed count sort
// S1: per-chunk histogram over coarse buckets, bucket-major output
__launch_bounds__(1024)
__global__ void k_hist(const int* __restrict__ dst, int* __restrict__ hist,
                       int E, int C, int NB) {
    __shared__ int h[1024];
    const int tid = threadIdx.x, c = blockIdx.x;
    for (int i = tid; i < NB; i += 1024) h[i] = 0;
    __syncthreads();
    const int e0 = c * CHUNK, e1 = min(e0 + CHUNK, E);
    for (int e = e0 + tid; e < e1; e += 1024) atomicAdd(&h[dst[e] >> SH], 1);
    __syncthreads();
    for (int b = tid; b < NB; b += 1024) hist[b * C + c] = h[b];
}

// S2a: per-segment sums
__launch_bounds__(256)
__global__ void k_scanA(const int* __restrict__ hist, int* __restrict__ bsum, int M) {
    __shared__ int part[256];
    const int b = blockIdx.x, t = threadIdx.x;
    const int seg = (M + SCANB - 1) / SCANB;
    const int lo = b * seg, hi = min(lo + seg, M);
    int s = 0;
    for (int i = lo + t; i < hi; i += 256) s += hist[i];
    part[t] = s;
    __syncthreads();
    for (int d = 128; d > 0; d >>= 1) {
        if (t < d) part[t] += part[t + d];
        __syncthreads();
    }
    if (t == 0) bsum[b] = part[0];
}

// S2b: exclusive scan of bsum[SCANB], single block
__launch_bounds__(256)
__global__ void k_scanB(int* __restrict__ bsum) {
    __shared__ int sh[256];
    const int t = threadIdx.x;
    sh[t] = bsum[t];
    __syncthreads();
    for (int d = 1; d < 256; d <<= 1) {
        int v = (t >= d) ? sh[t - d] : 0;
        __syncthreads();
        sh[t] += v;
        __syncthreads();
    }
    bsum[t] = (t == 0) ? 0 : sh[t - 1];
}

// S2c: per-segment exclusive scan (in place) + bsum offset; off[N]=E
__launch_bounds__(256)
__global__ void k_scanC(int* __restrict__ hist, const int* __restrict__ bsum,
                        int* __restrict__ off, int M, int E, int N) {
    __shared__ int part[256];
    const int b = blockIdx.x, t = threadIdx.x;
    const int seg = (M + SCANB - 1) / SCANB;
    const int lo = b * seg, hi = min(lo + seg, M);
    const int per = (seg + 255) >> 8;
    const int tl = lo + t * per, th = min(tl + per, hi);
    int s = 0;
    for (int i = tl; i < th; ++i) s += hist[i];
    part[t] = s;
    __syncthreads();
    for (int d = 1; d < 256; d <<= 1) {
        int v = (t >= d) ? part[t - d] : 0;
        __syncthreads();
        part[t] += v;
        __syncthreads();
    }
    int run = bsum[b] + ((t == 0) ? 0 : part[t - 1]);
    for (int i = tl; i < th; ++i) {
        int v = hist[i];
        hist[i] = run;
        run += v;
    }
    if (b == 0 && t == 0) off[N] = E;
}

// S3: scatter packed (dstloc<<18|src) into bucket-grouped order
__launch_bounds__(1024)
__global__ void k_sort(const int* __restrict__ src, const int* __restrict__ dst,
                       const int* __restrict__ hist, int* __restrict__ spk,
                       int E, int C, int NB) {
    __shared__ int cur[1024];
    const int tid = threadIdx.x, c = blockIdx.x;
    for (int b = tid; b < NB; b += 1024) cur[b] = hist[b * C + c];
    __syncthreads();
    const int e0 = c * CHUNK, e1 = min(e0 + CHUNK, E);
    for (int e = e0 + tid; e < e1; e += 1024) {
        const int d = dst[e];
        const int pos = atomicAdd(&cur[d >> SH], 1);
        spk[pos] = ((d & 127) << 18) | src[e];
    }
}

// S4: one block per bucket -> per-node counts, off[], dis[], and final eda
__launch_bounds__(256)
__global__ void k_csr(const int* __restrict__ spk, const int* __restrict__ hist,
                      int* __restrict__ off, float* __restrict__ dis,
                      int* __restrict__ eda, int E, int C, int NB, int N) {
    __shared__ int cnt_l[128], scn[128];
    const int tid = threadIdx.x, b = blockIdx.x;
    const int node0 = b << SH;
    const int nloc = min(128, N - node0);
    const int ebeg = hist[b * C];
    const int eend = (b + 1 < NB) ? hist[(b + 1) * C] : E;
    if (tid < 128) cnt_l[tid] = 0;
    __syncthreads();
    for (int e = ebeg + tid; e < eend; e += 256) {
        atomicAdd(&cnt_l[spk[e] >> 18], 1);
    }
    __syncthreads();
    if (tid < 128) scn[tid] = cnt_l[tid];
    __syncthreads();
    for (int d = 1; d < 128; d <<= 1) {
        int v = 0;
        if (tid < 128 && tid >= d) v = scn[tid - d];
        __syncthreads();
        if (tid < 128) scn[tid] += v;
        __syncthreads();
    }
    if (tid < nloc) {
        const int excl = scn[tid] - cnt_l[tid];
        off[node0 + tid] = ebeg + excl;
        dis[node0 + tid] = rsqrtf((float)cnt_l[tid] + 1.0f);
    }
    __syncthreads();
    if (tid < 128) cnt_l[tid] = scn[tid] - cnt_l[tid];  // reuse as cursor
    __syncthreads();
    for (int e = ebeg + tid; e < eend; e += 256) {
        const int p = spk[e];
        const int r = atomicAdd(&cnt_l[p >> 18], 1);
        eda[ebeg + r] = p & 0x3FFFF;
    }
}

// ----------------------------------------------------- layer-0 special path
// x0s4[w] = dis[w] * x0[w]  (3 ch padded to float4)
__global__ void k_prex(const float* __restrict__ x0, const float* __restrict__ dis,
                       float4* __restrict__ x0s4, int N) {
    int i = blockIdx.x * blockDim.x + threadIdx.x;
    if (i >= N) return;
    const float d = dis[i];
    x0s4[i] = make_float4(d * x0[3 * i], d * x0[3 * i + 1], d * x0[3 * i + 2], 0.f);
}

// z4[w] = dis[w] * (x0s4[w] + sum_src x0s4[src])   (wave per node)
__launch_bounds__(256)
__global__ void k_gather3(const int* __restrict__ off, const int* __restrict__ eda,
                          const float* __restrict__ dis, const float4* __restrict__ x0s4,
                          float4* __restrict__ z4, int N) {
    const int lane = threadIdx.x & 63, wv = threadIdx.x >> 6;
    const int nw = gridDim.x * 4;
    for (int w = blockIdx.x * 4 + wv; w < N; w += nw) {
        const int e0 = off[w], e1 = off[w + 1];
        float a0 = 0.f, a1 = 0.f, a2 = 0.f;
        for (int e = e0 + lane; e < e1; e += 64) {
            float4 v = x0s4[eda[e]];
            a0 += v.x;
            a1 += v.y;
            a2 += v.z;
        }
        for (int d = 32; d; d >>= 1) {
            a0 += __shfl_xor(a0, d);
            a1 += __shfl_xor(a1, d);
            a2 += __shfl_xor(a2, d);
        }
        if (lane == 0) {
            const float4 sv = x0s4[w];
            const float dw = dis[w];
            z4[w] = make_float4(dw * (a0 + sv.x), dw * (a1 + sv.y), dw * (a2 + sv.z), 0.f);
        }
    }
}

// bufA = z4(N,3) @ W0(3,64), fused BN stats
__launch_bounds__(256)
__global__ void k_lin0(const float4* __restrict__ z4, const float* __restrict__ W,
                       float* __restrict__ bufA, float* __restrict__ st, int N) {
    __shared__ float Ws[3 * 64];
    __shared__ float ls[256], lq[256];
    const int tid = threadIdx.x;
    for (int i = tid; i < 192; i += 256) Ws[i] = W[i];
    __syncthreads();
    const int c = tid & 63, wv = tid >> 6;
    float s = 0.f, q = 0.f;
    for (int r = blockIdx.x * 4 + wv; r < N; r += gridDim.x * 4) {
        const float4 zr = z4[r];
        float acc = zr.x * Ws[c] + zr.y * Ws[64 + c] + zr.z * Ws[128 + c];
        bufA[(long)r * 64 + c] = acc;
        s += acc;
        q = fmaf(acc, acc, q);
    }
    ls[tid] = s;
    lq[tid] = q;
    __syncthreads();
    if (tid < 64) {
        s = ls[c] + ls[c + 64] + ls[c + 128] + ls[c + 192];
        q = lq[c] + lq[c + 64] + lq[c + 128] + lq[c + 192];
        unsafeAtomicAdd(&st[c], s);
        unsafeAtomicAdd(&st[64 + c], q);
    }
}

// --------------------------------------------------- fused (BN+ReLU) + linear
// hp = (act(X)(N,64) @ W(64,64)) * dis[row]  stored fp16.
__launch_bounds__(256)
__global__ void k_linear(const float* __restrict__ X, const float* __restrict__ W,
                         const float* __restrict__ st, const float* __restrict__ g,
                         const float* __restrict__ be, const float* __restrict__ dis,
                         __half* __restrict__ hp, int N) {
    __shared__ float Ws[64 * 64];
    __shared__ float Xs[32 * 64];
    __shared__ float scs[64], shs[64];
    const int tid = threadIdx.x;
    if (tid < 64) {
        const float inv = 1.0f / (float)N;
        const float m = st[tid] * inv;
        const float v = st[64 + tid] * inv - m * m;
        const float sc = g[tid] * rsqrtf(v + EPSBN);
        scs[tid] = sc;
        shs[tid] = fmaf(-m, sc, be[tid]);
    }
    for (int i = tid; i < 64 * 64; i += 256) Ws[i] = W[i];
    __syncthreads();
    const int r0 = blockIdx.x * 32;
    for (int i = tid; i < 32 * 64; i += 256) {
        const int r = i >> 6, c = i & 63;
        const int row = r0 + r;
        float val = (row < N) ? X[(long)row * 64 + c] : 0.f;
        Xs[i] = fmaxf(fmaf(val, scs[c], shs[c]), 0.f);
    }
    __syncthreads();
    const int c = tid & 63, wv = tid >> 6;
    for (int rr = 0; rr < 8; ++rr) {
        const int r = wv * 8 + rr;
        const int row = r0 + r;
        if (row >= N) break;
        float acc = 0.f;
#pragma unroll
        for (int k = 0; k < 64; ++k) acc = fmaf(Xs[r * 64 + k], Ws[k * 64 + c], acc);
        hp[(long)row * 64 + c] = __float2half(acc * dis[row]);
    }
}

// ------------------------------------------- CSR aggregation + fused BN stats
// one wave per node (grid-stride), scalar half loads, 8-deep unroll / 4 accs
__launch_bounds__(256)
__global__ void k_gather(const int* __restrict__ off, const int* __restrict__ eda,
                         const float* __restrict__ dis, const __half* __restrict__ hp,
                         float* __restrict__ agg, float* __restrict__ st, int N) {
    __shared__ int els[4][64];
    __shared__ float ls[256], ls2[256];
    const int lane = threadIdx.x & 63;
    const int wv = threadIdx.x >> 6;
    const int nwaves = gridDim.x * 4;
    float s = 0.f, s2 = 0.f;
    for (int w = blockIdx.x * 4 + wv; w < N; w += nwaves) {
        const int e0 = off[w], e1 = off[w + 1];
        float acc0 = __half2float(hp[(long)w * 64 + lane]);
        float acc1 = 0.f, acc2 = 0.f, acc3 = 0.f;
        for (int eb = e0; eb < e1; eb += 64) {
            const int mm = min(64, e1 - eb);
            if (eb + lane < e1) els[wv][lane] = eda[eb + lane];
            int j = 0;
            for (; j + 8 <= mm; j += 8) {
                const int s0 = els[wv][j + 0], s1 = els[wv][j + 1];
                const int s2i = els[wv][j + 2], s3 = els[wv][j + 3];
                const int s4 = els[wv][j + 4], s5 = els[wv][j + 5];
                const int s6 = els[wv][j + 6], s7 = els[wv][j + 7];
                const float v0 = __half2float(hp[(long)s0 * 64 + lane]);
                const float v1 = __half2float(hp[(long)s1 * 64 + lane]);
                const float v2 = __half2float(hp[(long)s2i * 64 + lane]);
                const float v3 = __half2float(hp[(long)s3 * 64 + lane]);
                const float v4 = __half2float(hp[(long)s4 * 64 + lane]);
                const float v5 = __half2float(hp[(long)s5 * 64 + lane]);
                const float v6 = __half2float(hp[(long)s6 * 64 + lane]);
                const float v7 = __half2float(hp[(long)s7 * 64 + lane]);
                acc0 += v0 + v4;
                acc1 += v1 + v5;
                acc2 += v2 + v6;
                acc3 += v3 + v7;
            }
            for (; j < mm; ++j) acc0 += __half2float(hp[(long)els[wv][j] * 64 + lane]);
        }
        const float out = dis[w] * ((acc0 + acc1) + (acc2 + acc3));
        agg[(long)w * 64 + lane] = out;
        s += out;
        s2 = fmaf(out, out, s2);
    }
    ls[threadIdx.x] = s;
    ls2[threadIdx.x] = s2;
    __syncthreads();
    if (threadIdx.x < 64) {
        s = ls[lane] + ls[lane + 64] + ls[lane + 128] + ls[lane + 192];
        s2 = ls2[lane] + ls2[lane + 64] + ls2[lane + 128] + ls2[lane + 192];
        unsafeAtomicAdd(&st[lane], s);
        unsafeAtomicAdd(&st[64 + lane], s2);
    }
}

// ----------------------------------------------------- pooling (fused BN+ReLU)
__launch_bounds__(256)
__global__ void k_pool(const float* __restrict__ x, const int* __restrict__ batch,
                       const float* __restrict__ st, const float* __restrict__ g,
                       const float* __restrict__ be, float* __restrict__ poolsum,
                       float* __restrict__ counts, int N, int npw) {
    const int wid = (blockIdx.x * blockDim.x + threadIdx.x) >> 6;
    const int lane = threadIdx.x & 63;
    const int n0 = wid * npw;
    if (n0 >= N) return;
    const float inv = 1.0f / (float)N;
    const float m = st[lane] * inv;
    const float v = st[64 + lane] * inv - m * m;
    const float sc = g[lane] * rsqrtf(v + EPSBN);
    const float sh = fmaf(-m, sc, be[lane]);
    const int n1 = min(n0 + npw, N);
    float acc = 0.f, cnt = 0.f;
    int gr = batch[n0];
    for (int n = n0; n < n1; ++n) {
        int gn = batch[n];
        if (gn != gr) {
            unsafeAtomicAdd(&poolsum[(long)gr * 64 + lane], acc);
            if (lane == 0) unsafeAtomicAdd(&counts[gr], cnt);
            acc = 0.f;
            cnt = 0.f;
            gr = gn;
        }
        acc += fmaxf(fmaf(x[(long)n * 64 + lane], sc, sh), 0.f);
        cnt += 1.f;
    }
    unsafeAtomicAdd(&poolsum[(long)gr * 64 + lane], acc);
    if (lane == 0) unsafeAtomicAdd(&counts[gr], cnt);
}

// --------------------------------------------------------------------- heads
__launch_bounds__(256)
__global__ void k_heads(const float* __restrict__ poolsum, const float* __restrict__ counts,
                        const float* pW1, const float* pb1, const float* pW2, const float* pb2,
                        const float* aW1, const float* ab1, const float* aW2, const float* ab2,
                        const float* tW1, const float* tb1, const float* tW2, const float* tb2,
                        float* __restrict__ out, int G) {
    __shared__ float P[64 * 64];
    __shared__ float Hd[64 * 32];
    const int tid = threadIdx.x;
    for (int i = tid; i < G * 64; i += 256) {
        int g = i >> 6;
        P[i] = poolsum[i] / fmaxf(counts[g], 1.f);
    }
    __syncthreads();
    for (int j = 0; j < 3; ++j) {
        const float* W1 = (j == 0) ? pW1 : (j == 1) ? aW1 : tW1;
        const float* b1 = (j == 0) ? pb1 : (j == 1) ? ab1 : tb1;
        const float* W2 = (j == 0) ? pW2 : (j == 1) ? aW2 : tW2;
        const float* b2 = (j == 0) ? pb2 : (j == 1) ? ab2 : tb2;
        for (int i = tid; i < G * 32; i += 256) {
            int g = i >> 5, k = i & 31;
            float a = b1[k];
#pragma unroll
            for (int c = 0; c < 64; ++c) a = fmaf(P[g * 64 + c], W1[c * 32 + k], a);
            Hd[i] = fmaxf(a, 0.f);
        }
        __syncthreads();
        const int ow = (j == 2) ? 2 : 1;
        const int off = (j == 2) ? 2 : j;
        for (int i = tid; i < G * ow; i += 256) {
            int g = i / ow, o = i - g * ow;
            float a = b2[o];
#pragma unroll
            for (int k = 0; k < 32; ++k) a = fmaf(Hd[g * 32 + k], W2[k * ow + o], a);
            out[g * 4 + off + o] = a;
        }
        __syncthreads();
    }
}

// ====================================================================== host
extern "C" void kernel_launch(void* const* d_in, const int* in_sizes, int n_in,
                              void* d_out, int out_size, void* d_ws, size_t ws_size,
                              hipStream_t stream) {
    const int N = in_sizes[2];      // batch has N entries
    const int E = in_sizes[1] / 2;  // edge_index is [2, E]
    const int G = out_size / 4;     // output [G, 4]

    const float* x0 = (const float*)d_in[0];
    const int* ei = (const int*)d_in[1];
    const int* src = ei;
    const int* dst = ei + E;
    const int* batch = (const int*)d_in[2];

    const float* W[3] = {(const float*)d_in[3], (const float*)d_in[7], (const float*)d_in[11]};
    const float* gam[3] = {(const float*)d_in[5], (const float*)d_in[9], (const float*)d_in[13]};
    const float* bet[3] = {(const float*)d_in[6], (const float*)d_in[10], (const float*)d_in[14]};

    const float* pW1 = (const float*)d_in[15];
    const float* pb1 = (const float*)d_in[16];
    const float* pW2 = (const float*)d_in[17];
    const float* pb2 = (const float*)d_in[18];
    const float* aW1 = (const float*)d_in[19];
    const float* ab1 = (const float*)d_in[20];
    const float* aW2 = (const float*)d_in[21];
    const float* ab2 = (const float*)d_in[22];
    const float* tW1 = (const float*)d_in[23];
    const float* tb1 = (const float*)d_in[24];
    const float* tW2 = (const float*)d_in[25];
    const float* tb2 = (const float*)d_in[26];

    const int C = (E + CHUNK - 1) / CHUNK;   // sort chunks
    const int NB = (N + 127) >> SH;          // coarse buckets
    const int M = NB * C;

    // ---- workspace carve (256B aligned)
    auto align = [](size_t x) { return (x + 255) & ~(size_t)255; };
    char* w = (char*)d_ws;
    float* dis = (float*)w;      w += align((size_t)N * 4);
    float* bufA = (float*)w;     w += align((size_t)N * 64 * 4);   // fp32 agg
    __half* hp = (__half*)w;     w += align((size_t)N * 64 * 2);   // fp16 messages
    float* st = (float*)w;       w += align(3 * 128 * 4);          // st0,st1,st2
    float* poolsum = (float*)w;  w += align((size_t)G * 64 * 4);
    float* counts = (float*)w;   w += align((size_t)G * 4);
    int* off = (int*)w;          w += align((size_t)(N + 1) * 4);
    int* hist = (int*)w;         w += align((size_t)M * 4);
    int* bsum = (int*)w;         w += align((size_t)SCANB * 4);
    int* spk = (int*)w;          w += align((size_t)E * 4);        // packed sort
    int* eda = (int*)w;          w += align((size_t)E * 4);
    float4* x0s4 = (float4*)w;   w += align((size_t)N * 16);
    float4* z4 = (float4*)w;     w += align((size_t)N * 16);
    (void)ws_size;

    const int nbN = (N + 255) / 256;
    const int nb_lin = (N + 31) / 32;
    const int nb_ga = 2048;

    // ---- CSR build via bucketed counting sort (parallel scan, packed records)
    k_hist<<<C, 1024, 0, stream>>>(dst, hist, E, C, NB);
    k_scanA<<<SCANB, 256, 0, stream>>>(hist, bsum, M);
    k_scanB<<<1, 256, 0, stream>>>(bsum);
    k_scanC<<<SCANB, 256, 0, stream>>>(hist, bsum, off, M, E, N);
    k_sort<<<C, 1024, 0, stream>>>(src, dst, hist, spk, E, C, NB);
    k_csr<<<NB, 256, 0, stream>>>(spk, hist, off, dis, eda, E, C, NB, N);
    k_fill<<<2, 256, 0, stream>>>(st, 0.f, 3 * 128);

    // ---- layer 0: aggregate raw 3-channel input, then multiply W0 (+stats)
    k_prex<<<nbN, 256, 0, stream>>>(x0, dis, x0s4, N);
    k_gather3<<<512, 256, 0, stream>>>(off, eda, dis, x0s4, z4, N);
    k_lin0<<<1024, 256, 0, stream>>>(z4, W[0], bufA, st, N);

    // ---- layers 1,2 (K=64, BN of previous layer fused into staging)
    for (int l = 1; l < 3; ++l) {
        k_linear<<<nb_lin, 256, 0, stream>>>(bufA, W[l], st + (l - 1) * 128,
                                             gam[l - 1], bet[l - 1], dis, hp, N);
        k_gather<<<nb_ga, 256, 0, stream>>>(off, eda, dis, hp, bufA, st + l * 128, N);
    }

    // ---- global mean pool (BN of layer 2 fused)
    k_fill<<<(G * 64 + 255) / 256, 256, 0, stream>>>(poolsum, 0.f, G * 64);
    k_fill<<<1, 64, 0, stream>>>(counts, 0.f, G);
    const int npw = 32;
    const int nwaves = (N + npw - 1) / npw;
    const int nb_pool = (nwaves * 64 + 255) / 256;
    k_pool<<<nb_pool, 256, 0, stream>>>(bufA, batch, st + 256, gam[2], bet[2],
                                        poolsum, counts, N, npw);

    // ---- heads
    k_heads<<<1, 256, 0, stream>>>(poolsum, counts, pW1, pb1, pW2, pb2,
                                   aW1, ab1, aW2, ab2, tW1, tb1, tW2, tb2,
                                   (float*)d_out, G);
}

// Round 9
// 472.295 us; speedup vs baseline: 1.2610x; 1.0713x over previous
//
#include <hip/hip_runtime.h>
#include <hip/hip_fp16.h>

#define EPSBN 1e-5f
#define SH 7          // bucket = dst >> SH  (128 nodes per bucket)
#define CHUNK 16384   // edges per sort chunk
#define SCANB 256     // scan blocks

// ------------------------------------------------------- bucketed count sort
// S1: per-chunk histogram over coarse buckets, bucket-major output
__launch_bounds__(1024)
__global__ void k_hist(const int* __restrict__ dst, int* __restrict__ hist,
                       int E, int C, int NB) {
    __shared__ int h[1024];
    const int tid = threadIdx.x, c = blockIdx.x;
    for (int i = tid; i < NB; i += 1024) h[i] = 0;
    __syncthreads();
    const int e0 = c * CHUNK, e1 = min(e0 + CHUNK, E);
    for (int e = e0 + tid; e < e1; e += 1024) atomicAdd(&h[dst[e] >> SH], 1);
    __syncthreads();
    for (int b = tid; b < NB; b += 1024) hist[b * C + c] = h[b];
}

// S2a: per-segment sums
__launch_bounds__(256)
__global__ void k_scanA(const int* __restrict__ hist, int* __restrict__ bsum, int M) {
    __shared__ int part[256];
    const int b = blockIdx.x, t = threadIdx.x;
    const int seg = (M + SCANB - 1) / SCANB;
    const int lo = b * seg, hi = min(lo + seg, M);
    int s = 0;
    for (int i = lo + t; i < hi; i += 256) s += hist[i];
    part[t] = s;
    __syncthreads();
    for (int d = 128; d > 0; d >>= 1) {
        if (t < d) part[t] += part[t + d];
        __syncthreads();
    }
    if (t == 0) bsum[b] = part[0];
}

// S2b: exclusive scan of bsum[SCANB] + zero st/poolsum/counts
__launch_bounds__(256)
__global__ void k_scanB(int* __restrict__ bsum, float* __restrict__ st,
                        float* __restrict__ poolsum, float* __restrict__ counts, int G) {
    __shared__ int sh[256];
    const int t = threadIdx.x;
    sh[t] = bsum[t];
    __syncthreads();
    for (int d = 1; d < 256; d <<= 1) {
        int v = (t >= d) ? sh[t - d] : 0;
        __syncthreads();
        sh[t] += v;
        __syncthreads();
    }
    bsum[t] = (t == 0) ? 0 : sh[t - 1];
    for (int i = t; i < 3 * 128; i += 256) st[i] = 0.f;
    for (int i = t; i < G * 64; i += 256) poolsum[i] = 0.f;
    for (int i = t; i < G; i += 256) counts[i] = 0.f;
}

// S2c: per-segment exclusive scan (in place) + bsum offset; off[N]=E
__launch_bounds__(256)
__global__ void k_scanC(int* __restrict__ hist, const int* __restrict__ bsum,
                        int* __restrict__ off, int M, int E, int N) {
    __shared__ int part[256];
    const int b = blockIdx.x, t = threadIdx.x;
    const int seg = (M + SCANB - 1) / SCANB;
    const int lo = b * seg, hi = min(lo + seg, M);
    const int per = (seg + 255) >> 8;
    const int tl = lo + t * per, th = min(tl + per, hi);
    int s = 0;
    for (int i = tl; i < th; ++i) s += hist[i];
    part[t] = s;
    __syncthreads();
    for (int d = 1; d < 256; d <<= 1) {
        int v = (t >= d) ? part[t - d] : 0;
        __syncthreads();
        part[t] += v;
        __syncthreads();
    }
    int run = bsum[b] + ((t == 0) ? 0 : part[t - 1]);
    for (int i = tl; i < th; ++i) {
        int v = hist[i];
        hist[i] = run;
        run += v;
    }
    if (b == 0 && t == 0) off[N] = E;
}

// S3: scatter packed (dstloc<<18|src) into bucket-grouped order
__launch_bounds__(1024)
__global__ void k_sort(const int* __restrict__ src, const int* __restrict__ dst,
                       const int* __restrict__ hist, int* __restrict__ spk,
                       int E, int C, int NB) {
    __shared__ int cur[1024];
    const int tid = threadIdx.x, c = blockIdx.x;
    for (int b = tid; b < NB; b += 1024) cur[b] = hist[b * C + c];
    __syncthreads();
    const int e0 = c * CHUNK, e1 = min(e0 + CHUNK, E);
    for (int e = e0 + tid; e < e1; e += 1024) {
        const int d = dst[e];
        const int pos = atomicAdd(&cur[d >> SH], 1);
        spk[pos] = ((d & 127) << 18) | src[e];
    }
}

// S4: per bucket -> counts, off[], dis[], x0s4 (prex fused), and final eda
__launch_bounds__(256)
__global__ void k_csr(const int* __restrict__ spk, const int* __restrict__ hist,
                      const float* __restrict__ x0, int* __restrict__ off,
                      float* __restrict__ dis, float4* __restrict__ x0s4,
                      int* __restrict__ eda, int E, int C, int NB, int N) {
    __shared__ int cnt_l[128], scn[128];
    const int tid = threadIdx.x, b = blockIdx.x;
    const int node0 = b << SH;
    const int nloc = min(128, N - node0);
    const int ebeg = hist[b * C];
    const int eend = (b + 1 < NB) ? hist[(b + 1) * C] : E;
    if (tid < 128) cnt_l[tid] = 0;
    __syncthreads();
    for (int e = ebeg + tid; e < eend; e += 256) {
        atomicAdd(&cnt_l[spk[e] >> 18], 1);
    }
    __syncthreads();
    if (tid < 128) scn[tid] = cnt_l[tid];
    __syncthreads();
    for (int d = 1; d < 128; d <<= 1) {
        int v = 0;
        if (tid < 128 && tid >= d) v = scn[tid - d];
        __syncthreads();
        if (tid < 128) scn[tid] += v;
        __syncthreads();
    }
    if (tid < nloc) {
        const int excl = scn[tid] - cnt_l[tid];
        const int i = node0 + tid;
        const float d = rsqrtf((float)cnt_l[tid] + 1.0f);
        off[i] = ebeg + excl;
        dis[i] = d;
        x0s4[i] = make_float4(d * x0[3 * i], d * x0[3 * i + 1], d * x0[3 * i + 2], 0.f);
    }
    __syncthreads();
    if (tid < 128) cnt_l[tid] = scn[tid] - cnt_l[tid];  // reuse as cursor
    __syncthreads();
    for (int e = ebeg + tid; e < eend; e += 256) {
        const int p = spk[e];
        const int r = atomicAdd(&cnt_l[p >> 18], 1);
        eda[ebeg + r] = p & 0x3FFFF;
    }
}

// ------------------------- layer 0: gather(3ch) + @W0 + BN stats, all fused
// wave per node: z = dis[w]*(x0s4[w] + sum x0s4[src]); out[c=lane] = z . W0[:,c]
__launch_bounds__(256)
__global__ void k_gl0(const int* __restrict__ off, const int* __restrict__ eda,
                      const float* __restrict__ dis, const float4* __restrict__ x0s4,
                      const float* __restrict__ W0, float* __restrict__ bufA,
                      float* __restrict__ st, int N) {
    __shared__ float Ws[192];
    __shared__ float ls[256], lq[256];
    const int tid = threadIdx.x;
    const int lane = tid & 63, wv = tid >> 6;
    for (int i = tid; i < 192; i += 256) Ws[i] = W0[i];
    __syncthreads();
    const int nw = gridDim.x * 4;
    float s = 0.f, q = 0.f;
    for (int w = blockIdx.x * 4 + wv; w < N; w += nw) {
        const int e0 = off[w], e1 = off[w + 1];
        float a0 = 0.f, a1 = 0.f, a2 = 0.f;
        for (int e = e0 + lane; e < e1; e += 64) {
            float4 v = x0s4[eda[e]];
            a0 += v.x;
            a1 += v.y;
            a2 += v.z;
        }
#pragma unroll
        for (int d = 32; d; d >>= 1) {
            a0 += __shfl_xor(a0, d);
            a1 += __shfl_xor(a1, d);
            a2 += __shfl_xor(a2, d);
        }
        const float4 sv = x0s4[w];
        const float dw = dis[w];
        const float z0 = dw * (a0 + sv.x), z1 = dw * (a1 + sv.y), z2 = dw * (a2 + sv.z);
        const float val = z0 * Ws[lane] + z1 * Ws[64 + lane] + z2 * Ws[128 + lane];
        bufA[(long)w * 64 + lane] = val;
        s += val;
        q = fmaf(val, val, q);
    }
    ls[tid] = s;
    lq[tid] = q;
    __syncthreads();
    if (tid < 64) {
        s = ls[lane] + ls[lane + 64] + ls[lane + 128] + ls[lane + 192];
        q = lq[lane] + lq[lane + 64] + lq[lane + 128] + lq[lane + 192];
        unsafeAtomicAdd(&st[lane], s);
        unsafeAtomicAdd(&st[64 + lane], q);
    }
}

// --------------------------------------------------- fused (BN+ReLU) + linear
// hp = (act(X)(N,64) @ W(64,64)) * dis[row]  stored fp16.
__launch_bounds__(256)
__global__ void k_linear(const float* __restrict__ X, const float* __restrict__ W,
                         const float* __restrict__ st, const float* __restrict__ g,
                         const float* __restrict__ be, const float* __restrict__ dis,
                         __half* __restrict__ hp, int N) {
    __shared__ float Ws[64 * 64];
    __shared__ float Xs[32 * 64];
    __shared__ float scs[64], shs[64];
    const int tid = threadIdx.x;
    if (tid < 64) {
        const float inv = 1.0f / (float)N;
        const float m = st[tid] * inv;
        const float v = st[64 + tid] * inv - m * m;
        const float sc = g[tid] * rsqrtf(v + EPSBN);
        scs[tid] = sc;
        shs[tid] = fmaf(-m, sc, be[tid]);
    }
    for (int i = tid; i < 64 * 64; i += 256) Ws[i] = W[i];
    __syncthreads();
    const int r0 = blockIdx.x * 32;
    for (int i = tid; i < 32 * 64; i += 256) {
        const int r = i >> 6, c = i & 63;
        const int row = r0 + r;
        float val = (row < N) ? X[(long)row * 64 + c] : 0.f;
        Xs[i] = fmaxf(fmaf(val, scs[c], shs[c]), 0.f);
    }
    __syncthreads();
    const int c = tid & 63, wv = tid >> 6;
    for (int rr = 0; rr < 8; ++rr) {
        const int r = wv * 8 + rr;
        const int row = r0 + r;
        if (row >= N) break;
        float acc = 0.f;
#pragma unroll
        for (int k = 0; k < 64; ++k) acc = fmaf(Xs[r * 64 + k], Ws[k * 64 + c], acc);
        hp[(long)row * 64 + c] = __float2half(acc * dis[row]);
    }
}

// ------------------------------------------- CSR aggregation + fused BN stats
// 2-node interleave: wave processes nodes (p, p+P) simultaneously -> 8
// independent load/acc chains, per-node staging bubbles overlapped.
__launch_bounds__(256)
__global__ void k_gather(const int* __restrict__ off, const int* __restrict__ eda,
                         const float* __restrict__ dis, const __half* __restrict__ hp,
                         float* __restrict__ agg, float* __restrict__ st, int N) {
    __shared__ int els[4][2][64];
    __shared__ float ls[256], ls2[256];
    const int lane = threadIdx.x & 63;
    const int wv = threadIdx.x >> 6;
    const int nwaves = gridDim.x * 4;
    const int P = (N + 1) >> 1;
    float s = 0.f, s2 = 0.f;
    for (int p = blockIdx.x * 4 + wv; p < P; p += nwaves) {
        const int wA = p, wB = p + P;
        const bool hasB = (wB < N);
        const int a0o = off[wA];
        const int nA = off[wA + 1] - a0o;
        const int b0o = hasB ? off[wB] : 0;
        const int nB = hasB ? off[wB + 1] - b0o : 0;
        float accA0 = __half2float(hp[(long)wA * 64 + lane]);
        float accA1 = 0.f, accA2 = 0.f, accA3 = 0.f;
        float accB0 = hasB ? __half2float(hp[(long)wB * 64 + lane]) : 0.f;
        float accB1 = 0.f, accB2 = 0.f, accB3 = 0.f;
        const int nmax = nA > nB ? nA : nB;
        for (int base = 0; base < nmax; base += 64) {
            if (base + lane < nA) els[wv][0][lane] = eda[a0o + base + lane];
            if (base + lane < nB) els[wv][1][lane] = eda[b0o + base + lane];
            int mA = nA - base;
            mA = mA < 0 ? 0 : (mA > 64 ? 64 : mA);
            int mB = nB - base;
            mB = mB < 0 ? 0 : (mB > 64 ? 64 : mB);
            const int mc = mA < mB ? mA : mB;
            int j = 0;
            for (; j + 4 <= mc; j += 4) {
                const int sa0 = els[wv][0][j + 0], sa1 = els[wv][0][j + 1];
                const int sa2 = els[wv][0][j + 2], sa3 = els[wv][0][j + 3];
                const int sb0 = els[wv][1][j + 0], sb1 = els[wv][1][j + 1];
                const int sb2 = els[wv][1][j + 2], sb3 = els[wv][1][j + 3];
                const float va0 = __half2float(hp[(long)sa0 * 64 + lane]);
                const float va1 = __half2float(hp[(long)sa1 * 64 + lane]);
                const float va2 = __half2float(hp[(long)sa2 * 64 + lane]);
                const float va3 = __half2float(hp[(long)sa3 * 64 + lane]);
                const float vb0 = __half2float(hp[(long)sb0 * 64 + lane]);
                const float vb1 = __half2float(hp[(long)sb1 * 64 + lane]);
                const float vb2 = __half2float(hp[(long)sb2 * 64 + lane]);
                const float vb3 = __half2float(hp[(long)sb3 * 64 + lane]);
                accA0 += va0;
                accA1 += va1;
                accA2 += va2;
                accA3 += va3;
                accB0 += vb0;
                accB1 += vb1;
                accB2 += vb2;
                accB3 += vb3;
            }
            int jA = j, jB = j;
            for (; jA + 4 <= mA; jA += 4) {
                const int sa0 = els[wv][0][jA + 0], sa1 = els[wv][0][jA + 1];
                const int sa2 = els[wv][0][jA + 2], sa3 = els[wv][0][jA + 3];
                const float va0 = __half2float(hp[(long)sa0 * 64 + lane]);
                const float va1 = __half2float(hp[(long)sa1 * 64 + lane]);
                const float va2 = __half2float(hp[(long)sa2 * 64 + lane]);
                const float va3 = __half2float(hp[(long)sa3 * 64 + lane]);
                accA0 += va0;
                accA1 += va1;
                accA2 += va2;
                accA3 += va3;
            }
            for (; jA < mA; ++jA) accA0 += __half2float(hp[(long)els[wv][0][jA] * 64 + lane]);
            for (; jB + 4 <= mB; jB += 4) {
                const int sb0 = els[wv][1][jB + 0], sb1 = els[wv][1][jB + 1];
                const int sb2 = els[wv][1][jB + 2], sb3 = els[wv][1][jB + 3];
                const float vb0 = __half2float(hp[(long)sb0 * 64 + lane]);
                const float vb1 = __half2float(hp[(long)sb1 * 64 + lane]);
                const float vb2 = __half2float(hp[(long)sb2 * 64 + lane]);
                const float vb3 = __half2float(hp[(long)sb3 * 64 + lane]);
                accB0 += vb0;
                accB1 += vb1;
                accB2 += vb2;
                accB3 += vb3;
            }
            for (; jB < mB; ++jB) accB0 += __half2float(hp[(long)els[wv][1][jB] * 64 + lane]);
        }
        const float outA = dis[wA] * ((accA0 + accA1) + (accA2 + accA3));
        agg[(long)wA * 64 + lane] = outA;
        s += outA;
        s2 = fmaf(outA, outA, s2);
        if (hasB) {
            const float outB = dis[wB] * ((accB0 + accB1) + (accB2 + accB3));
            agg[(long)wB * 64 + lane] = outB;
            s += outB;
            s2 = fmaf(outB, outB, s2);
        }
    }
    ls[threadIdx.x] = s;
    ls2[threadIdx.x] = s2;
    __syncthreads();
    if (threadIdx.x < 64) {
        s = ls[lane] + ls[lane + 64] + ls[lane + 128] + ls[lane + 192];
        s2 = ls2[lane] + ls2[lane + 64] + ls2[lane + 128] + ls2[lane + 192];
        unsafeAtomicAdd(&st[lane], s);
        unsafeAtomicAdd(&st[64 + lane], s2);
    }
}

// ----------------------------------------------------- pooling (fused BN+ReLU)
__launch_bounds__(256)
__global__ void k_pool(const float* __restrict__ x, const int* __restrict__ batch,
                       const float* __restrict__ st, const float* __restrict__ g,
                       const float* __restrict__ be, float* __restrict__ poolsum,
                       float* __restrict__ counts, int N, int npw) {
    const int wid = (blockIdx.x * blockDim.x + threadIdx.x) >> 6;
    const int lane = threadIdx.x & 63;
    const int n0 = wid * npw;
    if (n0 >= N) return;
    const float inv = 1.0f / (float)N;
    const float m = st[lane] * inv;
    const float v = st[64 + lane] * inv - m * m;
    const float sc = g[lane] * rsqrtf(v + EPSBN);
    const float sh = fmaf(-m, sc, be[lane]);
    const int n1 = min(n0 + npw, N);
    float acc = 0.f, cnt = 0.f;
    int gr = batch[n0];
    for (int n = n0; n < n1; ++n) {
        int gn = batch[n];
        if (gn != gr) {
            unsafeAtomicAdd(&poolsum[(long)gr * 64 + lane], acc);
            if (lane == 0) unsafeAtomicAdd(&counts[gr], cnt);
            acc = 0.f;
            cnt = 0.f;
            gr = gn;
        }
        acc += fmaxf(fmaf(x[(long)n * 64 + lane], sc, sh), 0.f);
        cnt += 1.f;
    }
    unsafeAtomicAdd(&poolsum[(long)gr * 64 + lane], acc);
    if (lane == 0) unsafeAtomicAdd(&counts[gr], cnt);
}

// --------------------------------------------------------------------- heads
__launch_bounds__(256)
__global__ void k_heads(const float* __restrict__ poolsum, const float* __restrict__ counts,
                        const float* pW1, const float* pb1, const float* pW2, const float* pb2,
                        const float* aW1, const float* ab1, const float* aW2, const float* ab2,
                        const float* tW1, const float* tb1, const float* tW2, const float* tb2,
                        float* __restrict__ out, int G) {
    __shared__ float P[64 * 64];
    __shared__ float Hd[64 * 32];
    const int tid = threadIdx.x;
    for (int i = tid; i < G * 64; i += 256) {
        int g = i >> 6;
        P[i] = poolsum[i] / fmaxf(counts[g], 1.f);
    }
    __syncthreads();
    for (int j = 0; j < 3; ++j) {
        const float* W1 = (j == 0) ? pW1 : (j == 1) ? aW1 : tW1;
        const float* b1 = (j == 0) ? pb1 : (j == 1) ? ab1 : tb1;
        const float* W2 = (j == 0) ? pW2 : (j == 1) ? aW2 : tW2;
        const float* b2 = (j == 0) ? pb2 : (j == 1) ? ab2 : tb2;
        for (int i = tid; i < G * 32; i += 256) {
            int g = i >> 5, k = i & 31;
            float a = b1[k];
#pragma unroll
            for (int c = 0; c < 64; ++c) a = fmaf(P[g * 64 + c], W1[c * 32 + k], a);
            Hd[i] = fmaxf(a, 0.f);
        }
        __syncthreads();
        const int ow = (j == 2) ? 2 : 1;
        const int off = (j == 2) ? 2 : j;
        for (int i = tid; i < G * ow; i += 256) {
            int g = i / ow, o = i - g * ow;
            float a = b2[o];
#pragma unroll
            for (int k = 0; k < 32; ++k) a = fmaf(Hd[g * 32 + k], W2[k * ow + o], a);
            out[g * 4 + off + o] = a;
        }
        __syncthreads();
    }
}

// ====================================================================== host
extern "C" void kernel_launch(void* const* d_in, const int* in_sizes, int n_in,
                              void* d_out, int out_size, void* d_ws, size_t ws_size,
                              hipStream_t stream) {
    const int N = in_sizes[2];      // batch has N entries
    const int E = in_sizes[1] / 2;  // edge_index is [2, E]
    const int G = out_size / 4;     // output [G, 4]

    const float* x0 = (const float*)d_in[0];
    const int* ei = (const int*)d_in[1];
    const int* src = ei;
    const int* dst = ei + E;
    const int* batch = (const int*)d_in[2];

    const float* W[3] = {(const float*)d_in[3], (const float*)d_in[7], (const float*)d_in[11]};
    const float* gam[3] = {(const float*)d_in[5], (const float*)d_in[9], (const float*)d_in[13]};
    const float* bet[3] = {(const float*)d_in[6], (const float*)d_in[10], (const float*)d_in[14]};

    const float* pW1 = (const float*)d_in[15];
    const float* pb1 = (const float*)d_in[16];
    const float* pW2 = (const float*)d_in[17];
    const float* pb2 = (const float*)d_in[18];
    const float* aW1 = (const float*)d_in[19];
    const float* ab1 = (const float*)d_in[20];
    const float* aW2 = (const float*)d_in[21];
    const float* ab2 = (const float*)d_in[22];
    const float* tW1 = (const float*)d_in[23];
    const float* tb1 = (const float*)d_in[24];
    const float* tW2 = (const float*)d_in[25];
    const float* tb2 = (const float*)d_in[26];

    const int C = (E + CHUNK - 1) / CHUNK;   // sort chunks
    const int NB = (N + 127) >> SH;          // coarse buckets
    const int M = NB * C;

    // ---- workspace carve (256B aligned)
    auto align = [](size_t x) { return (x + 255) & ~(size_t)255; };
    char* w = (char*)d_ws;
    float* dis = (float*)w;      w += align((size_t)N * 4);
    float* bufA = (float*)w;     w += align((size_t)N * 64 * 4);   // fp32 agg
    __half* hp = (__half*)w;     w += align((size_t)N * 64 * 2);   // fp16 messages
    float* st = (float*)w;       w += align(3 * 128 * 4);          // st0,st1,st2
    float* poolsum = (float*)w;  w += align((size_t)G * 64 * 4);
    float* counts = (float*)w;   w += align((size_t)G * 4);
    int* off = (int*)w;          w += align((size_t)(N + 1) * 4);
    int* hist = (int*)w;         w += align((size_t)M * 4);
    int* bsum = (int*)w;         w += align((size_t)SCANB * 4);
    int* spk = (int*)w;          w += align((size_t)E * 4);        // packed sort
    int* eda = (int*)w;          w += align((size_t)E * 4);
    float4* x0s4 = (float4*)w;   w += align((size_t)N * 16);
    (void)ws_size;

    const int nb_lin = (N + 31) / 32;
    const int nb_ga = 2048;

    // ---- CSR build via bucketed counting sort (parallel scan, packed records)
    k_hist<<<C, 1024, 0, stream>>>(dst, hist, E, C, NB);
    k_scanA<<<SCANB, 256, 0, stream>>>(hist, bsum, M);
    k_scanB<<<1, 256, 0, stream>>>(bsum, st, poolsum, counts, G);
    k_scanC<<<SCANB, 256, 0, stream>>>(hist, bsum, off, M, E, N);
    k_sort<<<C, 1024, 0, stream>>>(src, dst, hist, spk, E, C, NB);
    k_csr<<<NB, 256, 0, stream>>>(spk, hist, x0, off, dis, x0s4, eda, E, C, NB, N);

    // ---- layer 0: fused 3-ch gather + @W0 + BN stats
    k_gl0<<<2048, 256, 0, stream>>>(off, eda, dis, x0s4, W[0], bufA, st, N);

    // ---- layers 1,2 (K=64, BN of previous layer fused into staging)
    for (int l = 1; l < 3; ++l) {
        k_linear<<<nb_lin, 256, 0, stream>>>(bufA, W[l], st + (l - 1) * 128,
                                             gam[l - 1], bet[l - 1], dis, hp, N);
        k_gather<<<nb_ga, 256, 0, stream>>>(off, eda, dis, hp, bufA, st + l * 128, N);
    }

    // ---- global mean pool (BN of layer 2 fused)
    const int npw = 32;
    const int nwaves = (N + npw - 1) / npw;
    const int nb_pool = (nwaves * 64 + 255) / 256;
    k_pool<<<nb_pool, 256, 0, stream>>>(bufA, batch, st + 256, gam[2], bet[2],
                                        poolsum, counts, N, npw);

    // ---- heads
    k_heads<<<1, 256, 0, stream>>>(poolsum, counts, pW1, pb1, pW2, pb2,
                                   aW1, ab1, aW2, ab2, tW1, tb1, tW2, tb2,
                                   (float*)d_out, G);
}